// Round 8
// baseline (883.041 us; speedup 1.0000x reference)
//
#include <hip/hip_runtime.h>
#include <math.h>

static inline size_t ws_align(size_t x) { return (x + 255) & ~(size_t)255; }

// ---------------- degree histogram ----------------
__global__ void count_kernel(const int* __restrict__ dst, int* __restrict__ counts, int E) {
  int e = blockIdx.x * 256 + threadIdx.x;
  if (e < E) atomicAdd(&counts[dst[e]], 1);
}

// ---------------- hierarchical scan: A) chunk sums ----------------
__global__ __launch_bounds__(256) void scanA_kernel(const int* __restrict__ counts,
    int* __restrict__ bsums, int n) {
  __shared__ int red[4];
  const int base = blockIdx.x * 1024;
  const int tid = threadIdx.x;
  int s = 0;
  #pragma unroll
  for (int u = 0; u < 4; ++u) {
    int i = base + u * 256 + tid;
    s += (i < n) ? counts[i] : 0;
  }
  #pragma unroll
  for (int m = 1; m < 64; m <<= 1) s += __shfl_xor(s, m, 64);
  if ((tid & 63) == 0) red[tid >> 6] = s;
  __syncthreads();
  if (tid == 0) bsums[blockIdx.x] = red[0] + red[1] + red[2] + red[3];
}

// ---------------- B) exclusive scan of chunk sums (nb <= 128) ----------------
__global__ __launch_bounds__(128) void scanB_kernel(int* __restrict__ bsums, int nb) {
  __shared__ int tmp[129];
  int tid = threadIdx.x;
  tmp[tid] = (tid < nb) ? bsums[tid] : 0;
  __syncthreads();
  if (tid == 0) {
    int run = 0;
    for (int i = 0; i < nb; ++i) { int v = tmp[i]; tmp[i] = run; run += v; }
  }
  __syncthreads();
  if (tid < nb) bsums[tid] = tmp[tid];
}

// ---------------- C) local scan + base; offsets/cursor/dinv ----------------
__global__ __launch_bounds__(1024) void scanC_kernel(const int* __restrict__ counts,
    const int* __restrict__ bsums, int* __restrict__ offsets, int* __restrict__ cursor,
    double* __restrict__ dinv, int n) {
  __shared__ int warpsums[16];
  const int tid = threadIdx.x;
  const int lane = tid & 63, wid = tid >> 6;
  const int i = blockIdx.x * 1024 + tid;
  int v = (i < n) ? counts[i] : 0;
  int x = v;
  #pragma unroll
  for (int d = 1; d < 64; d <<= 1) {
    int y = __shfl_up(x, d, 64);
    if (lane >= d) x += y;
  }
  if (lane == 63) warpsums[wid] = x;
  __syncthreads();
  if (wid == 0) {
    int w = (lane < 16) ? warpsums[lane] : 0;
    #pragma unroll
    for (int d = 1; d < 16; d <<= 1) {
      int y = __shfl_up(w, d, 64);
      if (lane >= d) w += y;
    }
    if (lane < 16) warpsums[lane] = w;
  }
  __syncthreads();
  int excl = bsums[blockIdx.x] + x - v + (wid > 0 ? warpsums[wid - 1] : 0);
  if (i < n) {
    offsets[i] = excl;
    cursor[i] = excl;
    dinv[i] = 1.0 / sqrt((double)(v + 1));   // deg = in-degree + self-loop, IEEE-exact
    if (i == n - 1) offsets[n] = excl + v;
  }
}

// ---------------- counting-sort scatter (+ optional per-edge weight, f32) ----------------
__global__ void scatter_kernel(const int* __restrict__ src, const int* __restrict__ dst,
    int* __restrict__ cursor, int* __restrict__ srcs, float* __restrict__ ew,
    const double* __restrict__ dinv, int E, int use_ew) {
  int e = blockIdx.x * 256 + threadIdx.x;
  if (e < E) {
    int s = src[e], d = dst[e];
    int p = atomicAdd(&cursor[d], 1);
    srcs[p] = s;
    if (use_ew) ew[p] = (float)(dinv[s] * dinv[d]);
  }
}

// ---------------- GEMM: out[N,H] = X[N,128] @ W[128,H], f32 storage, f64 accum ----------------
// 64 rows x H cols per 512-thread block; thread = 4 rows x H/32 cols.
// Staging uses lane<->row mapping so scalar k-major LDS writes are 2-way max
// (bank = (16*c4 + 4*j + r) mod 32, r spans 0..63). Reads: b128 stride-68, <=2-way.
// W f32 from global (16-lane dedup via L1), in-register cvt to f64, 2-deep ping-pong.
template<int H>
__global__ __launch_bounds__(512, 4) void gemm_kernel(const float* __restrict__ X,
    const float* __restrict__ W, float* __restrict__ out, int N) {
  __shared__ float xs[128 * 68];       // 34.8 KB, k-major stride 68
  const int tid  = threadIdx.x;
  const int row0 = blockIdx.x * 64;
  #pragma unroll
  for (int p = 0; p < 4; ++p) {
    int idx = p * 512 + tid;           // 2048 = 64 rows x 32 k-granules
    int r  = idx & 63;
    int c4 = idx >> 6;
    int grow = row0 + r;
    float4 v = make_float4(0.f, 0.f, 0.f, 0.f);
    if (grow < N) v = *(const float4*)(X + (size_t)grow * 128 + c4 * 4);
    float vals[4] = {v.x, v.y, v.z, v.w};
    #pragma unroll
    for (int j = 0; j < 4; ++j)
      xs[(4 * c4 + j) * 68 + r] = vals[j];
  }
  __syncthreads();
  constexpr int CPT = H / 32;          // 4 for H=128, 2 for H=64
  const int rowg = tid & 15;           // granule of 4 rows
  const int colg = tid >> 4;           // 0..31, CPT cols each
  const float* wbase = W + colg * CPT;

  double acc[4][CPT];
  #pragma unroll
  for (int j = 0; j < 4; ++j)
    #pragma unroll
    for (int h = 0; h < CPT; ++h) acc[j][h] = 0.0;

  float4 aA = *(const float4*)(xs + 4 * rowg);
  float4 aB;
  float bA[CPT], bB[CPT];
  #pragma unroll
  for (int h = 0; h < CPT; ++h) bA[h] = wbase[h];

  #pragma unroll 1
  for (int k = 0; k < 128; k += 2) {
    // prefetch k+1
    aB = *(const float4*)(xs + (k + 1) * 68 + 4 * rowg);
    #pragma unroll
    for (int h = 0; h < CPT; ++h) bB[h] = wbase[(size_t)(k + 1) * H + h];
    {
      double a0 = (double)aA.x, a1 = (double)aA.y, a2 = (double)aA.z, a3 = (double)aA.w;
      double b[CPT];
      #pragma unroll
      for (int h = 0; h < CPT; ++h) b[h] = (double)bA[h];
      #pragma unroll
      for (int h = 0; h < CPT; ++h) {
        acc[0][h] = fma(a0, b[h], acc[0][h]);
        acc[1][h] = fma(a1, b[h], acc[1][h]);
        acc[2][h] = fma(a2, b[h], acc[2][h]);
        acc[3][h] = fma(a3, b[h], acc[3][h]);
      }
    }
    // prefetch k+2
    if (k + 2 < 128) {
      aA = *(const float4*)(xs + (k + 2) * 68 + 4 * rowg);
      #pragma unroll
      for (int h = 0; h < CPT; ++h) bA[h] = wbase[(size_t)(k + 2) * H + h];
    }
    {
      double a0 = (double)aB.x, a1 = (double)aB.y, a2 = (double)aB.z, a3 = (double)aB.w;
      double b[CPT];
      #pragma unroll
      for (int h = 0; h < CPT; ++h) b[h] = (double)bB[h];
      #pragma unroll
      for (int h = 0; h < CPT; ++h) {
        acc[0][h] = fma(a0, b[h], acc[0][h]);
        acc[1][h] = fma(a1, b[h], acc[1][h]);
        acc[2][h] = fma(a2, b[h], acc[2][h]);
        acc[3][h] = fma(a3, b[h], acc[3][h]);
      }
    }
  }
  #pragma unroll
  for (int j = 0; j < 4; ++j) {
    int grow = row0 + rowg * 4 + j;
    if (grow < N) {
      float* o = out + (size_t)grow * H + colg * CPT;
      if constexpr (CPT == 4) {
        float4 v = make_float4((float)acc[j][0], (float)acc[j][1],
                               (float)acc[j][2], (float)acc[j][3]);
        *(float4*)o = v;
      } else {
        float2 v = make_float2((float)acc[j][0], (float)acc[j][1]);
        *(float2*)o = v;
      }
    }
  }
}

// ---------------- pull-style normalized aggregation (f32 rows, f64 accumulate) ----------------
template<int C, bool RELU, bool USE_EW>
__global__ __launch_bounds__(256) void gather_kernel(const float* __restrict__ xw,
    const double* __restrict__ dinv, const int* __restrict__ offs,
    const int* __restrict__ srcs, const float* __restrict__ ew,
    const float* __restrict__ bias, float* __restrict__ out, int N) {
  constexpr int LPR = C / 4;           // lanes per row: 32 (C=128), 16 (C=64)
  constexpr int EPI = 64 / LPR;        // edges per wave-iteration: 2 or 4
  constexpr int U = 8;
  const int node = blockIdx.x * 4 + (threadIdx.x >> 6);
  if (node >= N) return;
  const int lane = threadIdx.x & 63;
  const int grp  = lane / LPR;
  const int c0   = (lane % LPR) * 4;
  const int e0 = offs[node], e1 = offs[node + 1];
  const double di = dinv[node];
  double a0 = 0.0, a1 = 0.0, a2 = 0.0, a3 = 0.0;

  for (int base = e0; base < e1; base += U * EPI) {
    int ss[U];
    double ww[U];
    float4 vv[U];
    #pragma unroll
    for (int u = 0; u < U; ++u) {
      int ee = base + u * EPI + grp;
      int cl = ee < e1 ? ee : e1 - 1;
      ss[u] = srcs[cl];
      if (USE_EW) ww[u] = (double)ew[cl];
    }
    #pragma unroll
    for (int u = 0; u < U; ++u) {
      vv[u] = *(const float4*)(xw + (size_t)ss[u] * C + c0);
      if (!USE_EW) ww[u] = dinv[ss[u]];
    }
    #pragma unroll
    for (int u = 0; u < U; ++u) {
      int ee = base + u * EPI + grp;
      double w = (ee < e1) ? ww[u] : 0.0;
      a0 = fma(w, (double)vv[u].x, a0);
      a1 = fma(w, (double)vv[u].y, a1);
      a2 = fma(w, (double)vv[u].z, a2);
      a3 = fma(w, (double)vv[u].w, a3);
    }
  }
  #pragma unroll
  for (int m = LPR; m < 64; m <<= 1) {
    a0 += __shfl_xor(a0, m, 64);
    a1 += __shfl_xor(a1, m, 64);
    a2 += __shfl_xor(a2, m, 64);
    a3 += __shfl_xor(a3, m, 64);
  }
  if (grp == 0) {
    const double d2 = di * di;
    float4 sv = *(const float4*)(xw + (size_t)node * C + c0);
    float4 bv = *(const float4*)(bias + c0);
    double o0, o1, o2, o3;
    if (USE_EW) {
      o0 = a0 + fma(d2, (double)sv.x, (double)bv.x);
      o1 = a1 + fma(d2, (double)sv.y, (double)bv.y);
      o2 = a2 + fma(d2, (double)sv.z, (double)bv.z);
      o3 = a3 + fma(d2, (double)sv.w, (double)bv.w);
    } else {
      o0 = fma(di, a0, fma(d2, (double)sv.x, (double)bv.x));
      o1 = fma(di, a1, fma(d2, (double)sv.y, (double)bv.y));
      o2 = fma(di, a2, fma(d2, (double)sv.z, (double)bv.z));
      o3 = fma(di, a3, fma(d2, (double)sv.w, (double)bv.w));
    }
    if (RELU) {
      o0 = o0 > 0.0 ? o0 : 0.0; o1 = o1 > 0.0 ? o1 : 0.0;
      o2 = o2 > 0.0 ? o2 : 0.0; o3 = o3 > 0.0 ? o3 : 0.0;
    }
    *(float4*)(out + (size_t)node * C + c0) =
        make_float4((float)o0, (float)o1, (float)o2, (float)o3);
  }
}

// ---------------- per-graph top-30 sort pool (stable desc by ch 63) ----------------
__global__ __launch_bounds__(128) void sortpool_kernel(const float* __restrict__ h,
    float* __restrict__ out) {
  __shared__ float sv[128];
  __shared__ int si[128];
  int g = blockIdx.x;
  int tid = threadIdx.x;
  const float* hg = h + (size_t)g * 100 * 64;
  if (tid < 100) {
    sv[tid] = hg[tid * 64 + 63];
    si[tid] = tid;
  } else {
    sv[tid] = -3.0e38f;
    si[tid] = 1 << 30;
  }
  __syncthreads();
  for (int k = 2; k <= 128; k <<= 1) {
    for (int j = k >> 1; j > 0; j >>= 1) {
      int i = tid;
      int l = i ^ j;
      if (l > i) {
        float va = sv[i], vb = sv[l];
        int ia = si[i], ib = si[l];
        bool a_before_b = (va > vb) || (va == vb && ia < ib);  // strict total order
        bool up = ((i & k) == 0);
        bool sw = up ? !a_before_b : a_before_b;
        if (sw) { sv[i] = vb; sv[l] = va; si[i] = ib; si[l] = ia; }
      }
      __syncthreads();
    }
  }
  for (int t = tid; t < 30 * 64; t += 128) {
    int kk = t >> 6;
    int c = t & 63;
    out[(size_t)g * (30 * 64) + t] = hg[si[kk] * 64 + c];
  }
}

extern "C" void kernel_launch(void* const* d_in, const int* in_sizes, int n_in,
                              void* d_out, int out_size, void* d_ws, size_t ws_size,
                              hipStream_t stream) {
  const float* x  = (const float*)d_in[0];
  const int*   ei = (const int*)d_in[1];
  // d_in[2] = batch (unused: graphs contiguous, 100 nodes each)
  const float* W1 = (const float*)d_in[3];
  const float* b1 = (const float*)d_in[4];
  const float* W2 = (const float*)d_in[5];
  const float* b2 = (const float*)d_in[6];
  const float* W3 = (const float*)d_in[7];
  const float* b3 = (const float*)d_in[8];

  const int N = in_sizes[0] / 128;
  const int E = in_sizes[1] / 2;
  const int* src = ei;
  const int* dst = ei + E;
  (void)n_in; (void)out_size;

  const int nb = (N + 1023) / 1024;    // scan chunks (<=128 supported)

  char* ws = (char*)d_ws;
  size_t off = 0;
  auto alloc = [&](size_t bytes) { char* p = ws + off; off = ws_align(off + bytes); return p; };
  float*  xw      = (float*) alloc((size_t)N * 128 * 4);
  float*  h       = (float*) alloc((size_t)N * 128 * 4);
  double* dinv    = (double*)alloc((size_t)N * 8);
  int*    offsets = (int*)   alloc(((size_t)N + 1) * 4);
  int*    cursor  = (int*)   alloc((size_t)N * 4);
  int*    counts  = (int*)   alloc((size_t)N * 4);
  int*    srcs    = (int*)   alloc((size_t)E * 4);
  int*    bsums   = (int*)   alloc((size_t)(nb + 1) * 4);
  float*  ew      = (float*) alloc((size_t)E * 4);
  const bool use_ew = (off <= ws_size);   // ew is last; fall back if ws too small

  hipMemsetAsync(counts, 0, (size_t)N * 4, stream);
  count_kernel<<<(E + 255) / 256, 256, 0, stream>>>(dst, counts, E);
  scanA_kernel<<<nb, 256, 0, stream>>>(counts, bsums, N);
  scanB_kernel<<<1, 128, 0, stream>>>(bsums, nb);
  scanC_kernel<<<nb, 1024, 0, stream>>>(counts, bsums, offsets, cursor, dinv, N);
  scatter_kernel<<<(E + 255) / 256, 256, 0, stream>>>(src, dst, cursor, srcs, ew, dinv, E, use_ew ? 1 : 0);

  const int gblocks  = (N + 63) / 64;
  const int nblocks4 = (N + 3) / 4;

  gemm_kernel<128><<<gblocks, 512, 0, stream>>>(x, W1, xw, N);
  if (use_ew) {
    gather_kernel<128, true,  true><<<nblocks4, 256, 0, stream>>>(xw, dinv, offsets, srcs, ew, b1, h, N);
    gemm_kernel<128><<<gblocks, 512, 0, stream>>>(h, W2, xw, N);
    gather_kernel<128, true,  true><<<nblocks4, 256, 0, stream>>>(xw, dinv, offsets, srcs, ew, b2, h, N);
    gemm_kernel<64 ><<<gblocks, 512, 0, stream>>>(h, W3, xw, N);
    gather_kernel<64,  false, true><<<nblocks4, 256, 0, stream>>>(xw, dinv, offsets, srcs, ew, b3, h, N);
  } else {
    gather_kernel<128, true,  false><<<nblocks4, 256, 0, stream>>>(xw, dinv, offsets, srcs, ew, b1, h, N);
    gemm_kernel<128><<<gblocks, 512, 0, stream>>>(h, W2, xw, N);
    gather_kernel<128, true,  false><<<nblocks4, 256, 0, stream>>>(xw, dinv, offsets, srcs, ew, b2, h, N);
    gemm_kernel<64 ><<<gblocks, 512, 0, stream>>>(h, W3, xw, N);
    gather_kernel<64,  false, false><<<nblocks4, 256, 0, stream>>>(xw, dinv, offsets, srcs, ew, b3, h, N);
  }
  sortpool_kernel<<<N / 100, 128, 0, stream>>>(h, (float*)d_out);
}

// Round 11
// 847.244 us; speedup vs baseline: 1.0423x; 1.0423x over previous
//
#include <hip/hip_runtime.h>
#include <math.h>

static inline size_t ws_align(size_t x) { return (x + 255) & ~(size_t)255; }

// ---------------- degree histogram ----------------
__global__ void count_kernel(const int* __restrict__ dst, int* __restrict__ counts, int E) {
  int e = blockIdx.x * 256 + threadIdx.x;
  if (e < E) atomicAdd(&counts[dst[e]], 1);
}

// ---------------- hierarchical scan: A) chunk sums ----------------
__global__ __launch_bounds__(256) void scanA_kernel(const int* __restrict__ counts,
    int* __restrict__ bsums, int n) {
  __shared__ int red[4];
  const int base = blockIdx.x * 1024;
  const int tid = threadIdx.x;
  int s = 0;
  #pragma unroll
  for (int u = 0; u < 4; ++u) {
    int i = base + u * 256 + tid;
    s += (i < n) ? counts[i] : 0;
  }
  #pragma unroll
  for (int m = 1; m < 64; m <<= 1) s += __shfl_xor(s, m, 64);
  if ((tid & 63) == 0) red[tid >> 6] = s;
  __syncthreads();
  if (tid == 0) bsums[blockIdx.x] = red[0] + red[1] + red[2] + red[3];
}

// ---------------- B) exclusive scan of chunk sums (nb <= 128) ----------------
__global__ __launch_bounds__(128) void scanB_kernel(int* __restrict__ bsums, int nb) {
  __shared__ int tmp[129];
  int tid = threadIdx.x;
  tmp[tid] = (tid < nb) ? bsums[tid] : 0;
  __syncthreads();
  if (tid == 0) {
    int run = 0;
    for (int i = 0; i < nb; ++i) { int v = tmp[i]; tmp[i] = run; run += v; }
  }
  __syncthreads();
  if (tid < nb) bsums[tid] = tmp[tid];
}

// ---------------- C) local scan + base; offsets/cursor/dinv ----------------
__global__ __launch_bounds__(1024) void scanC_kernel(const int* __restrict__ counts,
    const int* __restrict__ bsums, int* __restrict__ offsets, int* __restrict__ cursor,
    double* __restrict__ dinv, int n) {
  __shared__ int warpsums[16];
  const int tid = threadIdx.x;
  const int lane = tid & 63, wid = tid >> 6;
  const int i = blockIdx.x * 1024 + tid;
  int v = (i < n) ? counts[i] : 0;
  int x = v;
  #pragma unroll
  for (int d = 1; d < 64; d <<= 1) {
    int y = __shfl_up(x, d, 64);
    if (lane >= d) x += y;
  }
  if (lane == 63) warpsums[wid] = x;
  __syncthreads();
  if (wid == 0) {
    int w = (lane < 16) ? warpsums[lane] : 0;
    #pragma unroll
    for (int d = 1; d < 16; d <<= 1) {
      int y = __shfl_up(w, d, 64);
      if (lane >= d) w += y;
    }
    if (lane < 16) warpsums[lane] = w;
  }
  __syncthreads();
  int excl = bsums[blockIdx.x] + x - v + (wid > 0 ? warpsums[wid - 1] : 0);
  if (i < n) {
    offsets[i] = excl;
    cursor[i] = excl;
    dinv[i] = 1.0 / sqrt((double)(v + 1));   // deg = in-degree + self-loop, IEEE-exact
    if (i == n - 1) offsets[n] = excl + v;
  }
}

// ---------------- counting-sort scatter (+ optional per-edge weight, f32) ----------------
__global__ void scatter_kernel(const int* __restrict__ src, const int* __restrict__ dst,
    int* __restrict__ cursor, int* __restrict__ srcs, float* __restrict__ ew,
    const double* __restrict__ dinv, int E, int use_ew) {
  int e = blockIdx.x * 256 + threadIdx.x;
  if (e < E) {
    int s = src[e], d = dst[e];
    int p = atomicAdd(&cursor[d], 1);
    srcs[p] = s;
    if (use_ew) ew[p] = (float)(dinv[s] * dinv[d]);
  }
}

// ---------------- GEMM1: out[N,H] = X[N,128] @ W[128,H] (round-8 structure) ----------------
template<int H>
__global__ __launch_bounds__(512, 4) void gemm_kernel(const float* __restrict__ X,
    const float* __restrict__ W, float* __restrict__ out, int N) {
  __shared__ float xs[128 * 68];       // 34.8 KB, k-major stride 68
  const int tid  = threadIdx.x;
  const int row0 = blockIdx.x * 64;
  #pragma unroll
  for (int p = 0; p < 4; ++p) {
    int idx = p * 512 + tid;           // 2048 = 64 rows x 32 k-granules
    int r  = idx & 63;
    int c4 = idx >> 6;
    int grow = row0 + r;
    float4 v = make_float4(0.f, 0.f, 0.f, 0.f);
    if (grow < N) v = *(const float4*)(X + (size_t)grow * 128 + c4 * 4);
    float vals[4] = {v.x, v.y, v.z, v.w};
    #pragma unroll
    for (int j = 0; j < 4; ++j)
      xs[(4 * c4 + j) * 68 + r] = vals[j];
  }
  __syncthreads();
  constexpr int CPT = H / 32;
  const int rowg = tid & 15;
  const int colg = tid >> 4;
  const float* wbase = W + colg * CPT;

  double acc[4][CPT];
  #pragma unroll
  for (int j = 0; j < 4; ++j)
    #pragma unroll
    for (int h = 0; h < CPT; ++h) acc[j][h] = 0.0;

  float4 aA = *(const float4*)(xs + 4 * rowg);
  float4 aB;
  float bA[CPT], bB[CPT];
  #pragma unroll
  for (int h = 0; h < CPT; ++h) bA[h] = wbase[h];

  #pragma unroll 1
  for (int k = 0; k < 128; k += 2) {
    aB = *(const float4*)(xs + (k + 1) * 68 + 4 * rowg);
    #pragma unroll
    for (int h = 0; h < CPT; ++h) bB[h] = wbase[(size_t)(k + 1) * H + h];
    {
      double a0 = (double)aA.x, a1 = (double)aA.y, a2 = (double)aA.z, a3 = (double)aA.w;
      double b[CPT];
      #pragma unroll
      for (int h = 0; h < CPT; ++h) b[h] = (double)bA[h];
      #pragma unroll
      for (int h = 0; h < CPT; ++h) {
        acc[0][h] = fma(a0, b[h], acc[0][h]);
        acc[1][h] = fma(a1, b[h], acc[1][h]);
        acc[2][h] = fma(a2, b[h], acc[2][h]);
        acc[3][h] = fma(a3, b[h], acc[3][h]);
      }
    }
    if (k + 2 < 128) {
      aA = *(const float4*)(xs + (k + 2) * 68 + 4 * rowg);
      #pragma unroll
      for (int h = 0; h < CPT; ++h) bA[h] = wbase[(size_t)(k + 2) * H + h];
    }
    {
      double a0 = (double)aB.x, a1 = (double)aB.y, a2 = (double)aB.z, a3 = (double)aB.w;
      double b[CPT];
      #pragma unroll
      for (int h = 0; h < CPT; ++h) b[h] = (double)bB[h];
      #pragma unroll
      for (int h = 0; h < CPT; ++h) {
        acc[0][h] = fma(a0, b[h], acc[0][h]);
        acc[1][h] = fma(a1, b[h], acc[1][h]);
        acc[2][h] = fma(a2, b[h], acc[2][h]);
        acc[3][h] = fma(a3, b[h], acc[3][h]);
      }
    }
  }
  #pragma unroll
  for (int j = 0; j < 4; ++j) {
    int grow = row0 + rowg * 4 + j;
    if (grow < N) {
      float* o = out + (size_t)grow * H + colg * CPT;
      if constexpr (CPT == 4) {
        *(float4*)o = make_float4((float)acc[j][0], (float)acc[j][1],
                                  (float)acc[j][2], (float)acc[j][3]);
      } else {
        *(float2*)o = make_float2((float)acc[j][0], (float)acc[j][1]);
      }
    }
  }
}

// ---------------- FUSED: h = relu(agg(xw_in)+bias); out = h @ Wn ----------------
// Phase A: each of 8 waves gathers 8 nodes (C_in=128, f64 accum), writes h rows
// into the GEMM's k-major LDS tile (stride 68). Phase B: round-8 GEMM from LDS.
// Across resident blocks, VMEM-bound gather overlaps VALU-bound GEMM.
template<int HOUT, bool USE_EW>
__global__ __launch_bounds__(512, 4) void fused_kernel(const float* __restrict__ xw_in,
    const double* __restrict__ dinv, const int* __restrict__ offs,
    const int* __restrict__ srcs, const float* __restrict__ ew,
    const float* __restrict__ bias, const float* __restrict__ Wn,
    float* __restrict__ xw_out, int N) {
  __shared__ float xs[128 * 68];       // 34.8 KB k-major h tile
  const int tid  = threadIdx.x;
  const int wave = tid >> 6, lane = tid & 63;
  const int row0 = blockIdx.x * 64;
  const int grp  = lane >> 5;          // 0..1 (EPI=2)
  const int c0   = (lane & 31) * 4;

  // ---- Phase A: gather ----
  for (int i = 0; i < 8; ++i) {
    const int n_loc = wave * 8 + i;
    const int node = row0 + n_loc;
    if (node >= N) break;
    const int e0 = offs[node], e1 = offs[node + 1];
    const double di = dinv[node];
    double a0 = 0.0, a1 = 0.0, a2 = 0.0, a3 = 0.0;
    for (int base = e0; base < e1; base += 16) {
      int ss[8]; double ww[8]; float4 vv[8];
      #pragma unroll
      for (int u = 0; u < 8; ++u) {
        int ee = base + u * 2 + grp;
        int cl = ee < e1 ? ee : e1 - 1;
        ss[u] = srcs[cl];
        if (USE_EW) ww[u] = (double)ew[cl];
      }
      #pragma unroll
      for (int u = 0; u < 8; ++u) {
        vv[u] = *(const float4*)(xw_in + (size_t)ss[u] * 128 + c0);
        if (!USE_EW) ww[u] = dinv[ss[u]];
      }
      #pragma unroll
      for (int u = 0; u < 8; ++u) {
        int ee = base + u * 2 + grp;
        double w = (ee < e1) ? ww[u] : 0.0;
        a0 = fma(w, (double)vv[u].x, a0);
        a1 = fma(w, (double)vv[u].y, a1);
        a2 = fma(w, (double)vv[u].z, a2);
        a3 = fma(w, (double)vv[u].w, a3);
      }
    }
    a0 += __shfl_xor(a0, 32, 64);
    a1 += __shfl_xor(a1, 32, 64);
    a2 += __shfl_xor(a2, 32, 64);
    a3 += __shfl_xor(a3, 32, 64);
    if (grp == 0) {
      const double d2 = di * di;
      float4 sv = *(const float4*)(xw_in + (size_t)node * 128 + c0);
      float4 bv = *(const float4*)(bias + c0);
      double o0, o1, o2, o3;
      if (USE_EW) {
        o0 = a0 + fma(d2, (double)sv.x, (double)bv.x);
        o1 = a1 + fma(d2, (double)sv.y, (double)bv.y);
        o2 = a2 + fma(d2, (double)sv.z, (double)bv.z);
        o3 = a3 + fma(d2, (double)sv.w, (double)bv.w);
      } else {
        o0 = fma(di, a0, fma(d2, (double)sv.x, (double)bv.x));
        o1 = fma(di, a1, fma(d2, (double)sv.y, (double)bv.y));
        o2 = fma(di, a2, fma(d2, (double)sv.z, (double)bv.z));
        o3 = fma(di, a3, fma(d2, (double)sv.w, (double)bv.w));
      }
      o0 = o0 > 0.0 ? o0 : 0.0; o1 = o1 > 0.0 ? o1 : 0.0;   // relu (layers 1,2)
      o2 = o2 > 0.0 ? o2 : 0.0; o3 = o3 > 0.0 ? o3 : 0.0;
      xs[(c0 + 0) * 68 + n_loc] = (float)o0;
      xs[(c0 + 1) * 68 + n_loc] = (float)o1;
      xs[(c0 + 2) * 68 + n_loc] = (float)o2;
      xs[(c0 + 3) * 68 + n_loc] = (float)o3;
    }
  }
  __syncthreads();

  // ---- Phase B: GEMM from LDS ----
  constexpr int CPT = HOUT / 32;
  const int rowg = tid & 15;
  const int colg = tid >> 4;
  const float* wbase = Wn + colg * CPT;

  double acc[4][CPT];
  #pragma unroll
  for (int j = 0; j < 4; ++j)
    #pragma unroll
    for (int h = 0; h < CPT; ++h) acc[j][h] = 0.0;

  float4 aA = *(const float4*)(xs + 4 * rowg);
  float4 aB;
  float bA[CPT], bB[CPT];
  #pragma unroll
  for (int h = 0; h < CPT; ++h) bA[h] = wbase[h];

  #pragma unroll 1
  for (int k = 0; k < 128; k += 2) {
    aB = *(const float4*)(xs + (k + 1) * 68 + 4 * rowg);
    #pragma unroll
    for (int h = 0; h < CPT; ++h) bB[h] = wbase[(size_t)(k + 1) * HOUT + h];
    {
      double a0 = (double)aA.x, a1 = (double)aA.y, a2 = (double)aA.z, a3 = (double)aA.w;
      double b[CPT];
      #pragma unroll
      for (int h = 0; h < CPT; ++h) b[h] = (double)bA[h];
      #pragma unroll
      for (int h = 0; h < CPT; ++h) {
        acc[0][h] = fma(a0, b[h], acc[0][h]);
        acc[1][h] = fma(a1, b[h], acc[1][h]);
        acc[2][h] = fma(a2, b[h], acc[2][h]);
        acc[3][h] = fma(a3, b[h], acc[3][h]);
      }
    }
    if (k + 2 < 128) {
      aA = *(const float4*)(xs + (k + 2) * 68 + 4 * rowg);
      #pragma unroll
      for (int h = 0; h < CPT; ++h) bA[h] = wbase[(size_t)(k + 2) * HOUT + h];
    }
    {
      double a0 = (double)aB.x, a1 = (double)aB.y, a2 = (double)aB.z, a3 = (double)aB.w;
      double b[CPT];
      #pragma unroll
      for (int h = 0; h < CPT; ++h) b[h] = (double)bB[h];
      #pragma unroll
      for (int h = 0; h < CPT; ++h) {
        acc[0][h] = fma(a0, b[h], acc[0][h]);
        acc[1][h] = fma(a1, b[h], acc[1][h]);
        acc[2][h] = fma(a2, b[h], acc[2][h]);
        acc[3][h] = fma(a3, b[h], acc[3][h]);
      }
    }
  }
  #pragma unroll
  for (int j = 0; j < 4; ++j) {
    int grow = row0 + rowg * 4 + j;
    if (grow < N) {
      float* o = xw_out + (size_t)grow * HOUT + colg * CPT;
      if constexpr (CPT == 4) {
        *(float4*)o = make_float4((float)acc[j][0], (float)acc[j][1],
                                  (float)acc[j][2], (float)acc[j][3]);
      } else {
        *(float2*)o = make_float2((float)acc[j][0], (float)acc[j][1]);
      }
    }
  }
}

// ---------------- FUSED: final gather (C=64, +bias, no relu) + top-30 sort pool ----------------
// One block per graph (100 nodes). 8 waves gather nodes (stride-8), rows to LDS,
// then bitonic top-k (stable desc by ch 63) and coalesced output.
template<bool USE_EW>
__global__ __launch_bounds__(512, 2) void gather_pool_kernel(const float* __restrict__ xw,
    const double* __restrict__ dinv, const int* __restrict__ offs,
    const int* __restrict__ srcs, const float* __restrict__ ew,
    const float* __restrict__ bias, float* __restrict__ out, int N) {
  __shared__ float hl[100 * 64];       // 25.6 KB
  __shared__ float sv[128];
  __shared__ int si[128];
  const int tid  = threadIdx.x;
  const int wave = tid >> 6, lane = tid & 63;
  const int g = blockIdx.x;
  const int grp = lane >> 4;           // 0..3 (EPI=4)
  const int c0  = (lane & 15) * 4;     // 0..60

  for (int n_loc = wave; n_loc < 100; n_loc += 8) {
    const int node = g * 100 + n_loc;
    const int e0 = offs[node], e1 = offs[node + 1];
    const double di = dinv[node];
    double a0 = 0.0, a1 = 0.0, a2 = 0.0, a3 = 0.0;
    for (int base = e0; base < e1; base += 16) {
      int ss[4]; double ww[4]; float4 vv[4];
      #pragma unroll
      for (int u = 0; u < 4; ++u) {
        int ee = base + u * 4 + grp;
        int cl = ee < e1 ? ee : e1 - 1;
        ss[u] = srcs[cl];
        if (USE_EW) ww[u] = (double)ew[cl];
      }
      #pragma unroll
      for (int u = 0; u < 4; ++u) {
        vv[u] = *(const float4*)(xw + (size_t)ss[u] * 64 + c0);
        if (!USE_EW) ww[u] = dinv[ss[u]];
      }
      #pragma unroll
      for (int u = 0; u < 4; ++u) {
        int ee = base + u * 4 + grp;
        double w = (ee < e1) ? ww[u] : 0.0;
        a0 = fma(w, (double)vv[u].x, a0);
        a1 = fma(w, (double)vv[u].y, a1);
        a2 = fma(w, (double)vv[u].z, a2);
        a3 = fma(w, (double)vv[u].w, a3);
      }
    }
    #pragma unroll
    for (int m = 16; m < 64; m <<= 1) {
      a0 += __shfl_xor(a0, m, 64);
      a1 += __shfl_xor(a1, m, 64);
      a2 += __shfl_xor(a2, m, 64);
      a3 += __shfl_xor(a3, m, 64);
    }
    if (grp == 0) {
      const double d2 = di * di;
      float4 svf = *(const float4*)(xw + (size_t)node * 64 + c0);
      float4 bv  = *(const float4*)(bias + c0);
      double o0, o1, o2, o3;
      if (USE_EW) {
        o0 = a0 + fma(d2, (double)svf.x, (double)bv.x);
        o1 = a1 + fma(d2, (double)svf.y, (double)bv.y);
        o2 = a2 + fma(d2, (double)svf.z, (double)bv.z);
        o3 = a3 + fma(d2, (double)svf.w, (double)bv.w);
      } else {
        o0 = fma(di, a0, fma(d2, (double)svf.x, (double)bv.x));
        o1 = fma(di, a1, fma(d2, (double)svf.y, (double)bv.y));
        o2 = fma(di, a2, fma(d2, (double)svf.z, (double)bv.z));
        o3 = fma(di, a3, fma(d2, (double)svf.w, (double)bv.w));
      }
      hl[n_loc * 64 + c0 + 0] = (float)o0;
      hl[n_loc * 64 + c0 + 1] = (float)o1;
      hl[n_loc * 64 + c0 + 2] = (float)o2;
      hl[n_loc * 64 + c0 + 3] = (float)o3;
    }
  }
  __syncthreads();
  if (tid < 128) {
    if (tid < 100) { sv[tid] = hl[tid * 64 + 63]; si[tid] = tid; }
    else           { sv[tid] = -3.0e38f;          si[tid] = 1 << 30; }
  }
  __syncthreads();
  for (int k = 2; k <= 128; k <<= 1) {
    for (int j = k >> 1; j > 0; j >>= 1) {
      if (tid < 128) {
        int l = tid ^ j;
        if (l > tid) {
          float va = sv[tid], vb = sv[l];
          int ia = si[tid], ib = si[l];
          bool a_before_b = (va > vb) || (va == vb && ia < ib);
          bool up = ((tid & k) == 0);
          bool sw = up ? !a_before_b : a_before_b;
          if (sw) { sv[tid] = vb; sv[l] = va; si[tid] = ib; si[l] = ia; }
        }
      }
      __syncthreads();
    }
  }
  for (int t = tid; t < 30 * 64; t += 512)
    out[(size_t)g * (30 * 64) + t] = hl[si[t >> 6] * 64 + (t & 63)];
}

extern "C" void kernel_launch(void* const* d_in, const int* in_sizes, int n_in,
                              void* d_out, int out_size, void* d_ws, size_t ws_size,
                              hipStream_t stream) {
  const float* x  = (const float*)d_in[0];
  const int*   ei = (const int*)d_in[1];
  // d_in[2] = batch (unused: graphs contiguous, 100 nodes each)
  const float* W1 = (const float*)d_in[3];
  const float* b1 = (const float*)d_in[4];
  const float* W2 = (const float*)d_in[5];
  const float* b2 = (const float*)d_in[6];
  const float* W3 = (const float*)d_in[7];
  const float* b3 = (const float*)d_in[8];

  const int N = in_sizes[0] / 128;
  const int E = in_sizes[1] / 2;
  const int* src = ei;
  const int* dst = ei + E;
  (void)n_in; (void)out_size;

  const int nb = (N + 1023) / 1024;    // scan chunks (<=128 supported)

  char* ws = (char*)d_ws;
  size_t off = 0;
  auto alloc = [&](size_t bytes) { char* p = ws + off; off = ws_align(off + bytes); return p; };
  float*  xw      = (float*) alloc((size_t)N * 128 * 4);
  float*  h       = (float*) alloc((size_t)N * 128 * 4);
  double* dinv    = (double*)alloc((size_t)N * 8);
  int*    offsets = (int*)   alloc(((size_t)N + 1) * 4);
  int*    cursor  = (int*)   alloc((size_t)N * 4);
  int*    counts  = (int*)   alloc((size_t)N * 4);
  int*    srcs    = (int*)   alloc((size_t)E * 4);
  int*    bsums   = (int*)   alloc((size_t)(nb + 1) * 4);
  float*  ew      = (float*) alloc((size_t)E * 4);
  const bool use_ew = (off <= ws_size);   // ew is last; fall back if ws too small

  hipMemsetAsync(counts, 0, (size_t)N * 4, stream);
  count_kernel<<<(E + 255) / 256, 256, 0, stream>>>(dst, counts, E);
  scanA_kernel<<<nb, 256, 0, stream>>>(counts, bsums, N);
  scanB_kernel<<<1, 128, 0, stream>>>(bsums, nb);
  scanC_kernel<<<nb, 1024, 0, stream>>>(counts, bsums, offsets, cursor, dinv, N);
  scatter_kernel<<<(E + 255) / 256, 256, 0, stream>>>(src, dst, cursor, srcs, ew, dinv, E, use_ew ? 1 : 0);

  const int gblocks = (N + 63) / 64;

  gemm_kernel<128><<<gblocks, 512, 0, stream>>>(x, W1, xw, N);
  if (use_ew) {
    fused_kernel<128, true ><<<gblocks, 512, 0, stream>>>(xw, dinv, offsets, srcs, ew, b1, W2, h, N);
    fused_kernel<64,  true ><<<gblocks, 512, 0, stream>>>(h,  dinv, offsets, srcs, ew, b2, W3, xw, N);
    gather_pool_kernel<true ><<<N / 100, 512, 0, stream>>>(xw, dinv, offsets, srcs, ew, b3, (float*)d_out, N);
  } else {
    fused_kernel<128, false><<<gblocks, 512, 0, stream>>>(xw, dinv, offsets, srcs, ew, b1, W2, h, N);
    fused_kernel<64,  false><<<gblocks, 512, 0, stream>>>(h,  dinv, offsets, srcs, ew, b2, W3, xw, N);
    gather_pool_kernel<false><<<N / 100, 512, 0, stream>>>(xw, dinv, offsets, srcs, ew, b3, (float*)d_out, N);
  }
}